// Round 6
// baseline (1059.245 us; speedup 1.0000x reference)
//
#include <hip/hip_runtime.h>
#include <hip/hip_cooperative_groups.h>
#include <hip/hip_fp16.h>
#include <cstdint>

namespace cg = cooperative_groups;

#define H 64
#define EPR 16        // edges per round in gat (16 -> 4KB tile/wave)
#define CSRB 960      // cooperative CSR-build blocks (<= co-residency cap 2048)

__device__ __forceinline__ float selu_f(float x) {
  const float sc = 1.0507009873554805f;
  const float al = 1.6732632423543772f;
  return x > 0.f ? sc * x : sc * al * (expf(x) - 1.f);
}

// ---------- split GEMM: 128 rows/block, one 64x64 W per block, 2 rows/thread ----------
// (verified round 5: -6.7 us/launch vs dual2)
__global__ __launch_bounds__(256) void gemm64_split(
    const float* __restrict__ Au, const float* __restrict__ Am,
    const float* __restrict__ W0u, const float* __restrict__ b0u,
    const float* __restrict__ W1u, const float* __restrict__ b1u,
    const float* __restrict__ W0m, const float* __restrict__ b0m,
    const float* __restrict__ W1m, const float* __restrict__ b1m,
    __half* __restrict__ C0u, float* __restrict__ C1u,
    __half* __restrict__ C0m, float* __restrict__ C1m,
    int Nu, int Nm, int su, int sm) {
  __shared__ float Ws[64 * 64];
  __shared__ float As[128][65];
  __shared__ float bs[64];

  const int b = blockIdx.x;
  const float *A, *W, *bias; __half* Ch = nullptr; float* Cf = nullptr;
  int N, blk; bool half_out;
  if (b < su)             { A = Au; W = W0u; bias = b0u; Ch = C0u; N = Nu; blk = b;             half_out = true; }
  else if (b < 2 * su)    { A = Au; W = W1u; bias = b1u; Cf = C1u; N = Nu; blk = b - su;        half_out = false; }
  else if (b < 2*su + sm) { A = Am; W = W0m; bias = b0m; Ch = C0m; N = Nm; blk = b - 2*su;      half_out = true; }
  else                    { A = Am; W = W1m; bias = b1m; Cf = C1m; N = Nm; blk = b - 2*su - sm; half_out = false; }

  const int tid = threadIdx.x;
  for (int i = tid; i < 1024; i += 256) ((float4*)Ws)[i] = ((const float4*)W)[i];
  if (tid < 64) bs[tid] = bias[tid];

  const int row0 = blk * 128;
  for (int i = tid; i < 2048; i += 256) {
    int r = i >> 4, c4 = i & 15;
    int row = row0 + r;
    float4 v = make_float4(0.f, 0.f, 0.f, 0.f);
    if (row < N) v = ((const float4*)(A + (size_t)row * H))[c4];
    As[r][c4 * 4 + 0] = v.x;
    As[r][c4 * 4 + 1] = v.y;
    As[r][c4 * 4 + 2] = v.z;
    As[r][c4 * 4 + 3] = v.w;
  }
  __syncthreads();

  const int g = tid & 3;    // 16-col group
  const int tr = tid >> 2;  // 0..63; rows tr and tr+64
  float acc0[16], acc1[16];
#pragma unroll
  for (int j = 0; j < 16; ++j) { acc0[j] = bs[g * 16 + j]; acc1[j] = bs[g * 16 + j]; }

  for (int k = 0; k < 64; ++k) {
    float a0 = As[tr][k];
    float a1 = As[tr + 64][k];
    const float4* wr = (const float4*)&Ws[k * 64 + g * 16];
#pragma unroll
    for (int c = 0; c < 4; ++c) {
      float4 w = wr[c];
      acc0[4 * c + 0] = fmaf(a0, w.x, acc0[4 * c + 0]);
      acc0[4 * c + 1] = fmaf(a0, w.y, acc0[4 * c + 1]);
      acc0[4 * c + 2] = fmaf(a0, w.z, acc0[4 * c + 2]);
      acc0[4 * c + 3] = fmaf(a0, w.w, acc0[4 * c + 3]);
      acc1[4 * c + 0] = fmaf(a1, w.x, acc1[4 * c + 0]);
      acc1[4 * c + 1] = fmaf(a1, w.y, acc1[4 * c + 1]);
      acc1[4 * c + 2] = fmaf(a1, w.z, acc1[4 * c + 2]);
      acc1[4 * c + 3] = fmaf(a1, w.w, acc1[4 * c + 3]);
    }
  }

#pragma unroll
  for (int half = 0; half < 2; ++half) {
    const int row = row0 + tr + 64 * half;
    if (row >= N) continue;
    const float* acc = half ? acc1 : acc0;
    if (half_out) {
      unsigned pu[8];
#pragma unroll
      for (int j2 = 0; j2 < 8; ++j2) {
        __half2 t = __floats2half2_rn(acc[2 * j2], acc[2 * j2 + 1]);
        pu[j2] = *(unsigned*)&t;
      }
      uint4* c0 = (uint4*)(Ch + (size_t)row * H + g * 16);
      c0[0] = make_uint4(pu[0], pu[1], pu[2], pu[3]);
      c0[1] = make_uint4(pu[4], pu[5], pu[6], pu[7]);
    } else {
      float4* c1 = (float4*)(Cf + (size_t)row * H + g * 16);
#pragma unroll
      for (int c = 0; c < 4; ++c)
        c1[c] = make_float4(acc[4 * c + 0], acc[4 * c + 1], acc[4 * c + 2], acc[4 * c + 3]);
    }
  }
}

// ---------- fused CSR build: ONE cooperative kernel (was 6 kernels) ----------
// Phase 1: global-atomic degree count (cnt zeroed by host memsetAsync).
// Phase 2: two-level exclusive scan -> rp (+ in-place cursor in cnt).
// Phase 3: direct atomic scatter -> csr (order within a dst nondeterministic;
//          round-3 evidence: absmax insensitive to per-dst sum order).
__global__ __launch_bounds__(256) void csr_build(
    const int* __restrict__ es1, const int* __restrict__ ed1,
    int E1, int nE1, int nd1, int* cnt1, int* rp1, int* csr1,
    const int* __restrict__ es2, const int* __restrict__ ed2,
    int E2, int nE2, int nd2, int* cnt2, int* rp2, int* csr2,
    int* csum, int C1, int C2) {
  cg::grid_group grid = cg::this_grid();
  __shared__ int sh[256];
  const int tid = threadIdx.x;
  const int gsz = gridDim.x;
  const int gid = blockIdx.x * 256 + tid;
  const int gstride = gsz * 256;

  // ---- phase 1: count degrees ----
  for (int e = gid; e < nE1; e += gstride) {
    int d = (e < E1) ? ed1[e] : (e - E1);
    atomicAdd(&cnt1[d], 1);
  }
  for (int e = gid; e < nE2; e += gstride) {
    int d = (e < E2) ? ed2[e] : (e - E2);
    atomicAdd(&cnt2[d], 1);
  }
  grid.sync();

  // ---- phase 2a: per-chunk inclusive scan -> rp[i+1] (pre-offset), csum[c] ----
  for (int c = blockIdx.x; c < C1 + C2; c += gsz) {
    const int* cnt; int* rp; int n; int lc;
    if (c < C1) { cnt = cnt1; rp = rp1; n = nd1; lc = c; }
    else        { cnt = cnt2; rp = rp2; n = nd2; lc = c - C1; }
    int i = lc * 256 + tid;
    int v = (i < n) ? cnt[i] : 0;
    __syncthreads();
    sh[tid] = v;
    __syncthreads();
    for (int off = 1; off < 256; off <<= 1) {
      int t = (tid >= off) ? sh[tid - off] : 0;
      __syncthreads();
      if (tid >= off) sh[tid] += t;
      __syncthreads();
    }
    if (i < n) rp[i + 1] = sh[tid];
    if (tid == 255) csum[c] = sh[255];
    __syncthreads();
  }
  grid.sync();

  // ---- phase 2b: block 0 exclusive-scans csum, per segment ----
  if (blockIdx.x == 0) {
    int run = 0;
    for (int start = 0; start < C1; start += 256) {
      int li = start + tid;
      int v = (li < C1) ? csum[li] : 0;
      __syncthreads();
      sh[tid] = v;
      __syncthreads();
      for (int off = 1; off < 256; off <<= 1) {
        int t = (tid >= off) ? sh[tid - off] : 0;
        __syncthreads();
        if (tid >= off) sh[tid] += t;
        __syncthreads();
      }
      if (li < C1) csum[li] = run + sh[tid] - v;  // exclusive
      run += sh[255];
      __syncthreads();
    }
    run = 0;
    for (int start = 0; start < C2; start += 256) {
      int li = start + tid;
      int v = (li < C2) ? csum[C1 + li] : 0;
      __syncthreads();
      sh[tid] = v;
      __syncthreads();
      for (int off = 1; off < 256; off <<= 1) {
        int t = (tid >= off) ? sh[tid - off] : 0;
        __syncthreads();
        if (tid >= off) sh[tid] += t;
        __syncthreads();
      }
      if (li < C2) csum[C1 + li] = run + sh[tid] - v;  // exclusive
      run += sh[255];
      __syncthreads();
    }
  }
  grid.sync();

  // ---- phase 2c: add chunk offsets; cursor = exclusive (reuse cnt in place) ----
  for (int c = blockIdx.x; c < C1 + C2; c += gsz) {
    int* cnt; int* rp; int n; int lc;
    if (c < C1) { cnt = cnt1; rp = rp1; n = nd1; lc = c; }
    else        { cnt = cnt2; rp = rp2; n = nd2; lc = c - C1; }
    int i = lc * 256 + tid;
    int off = csum[c];
    if (i < n) {
      int incl = rp[i + 1] + off;
      rp[i + 1] = incl;
      cnt[i] = incl - cnt[i];   // exclusive write cursor
      if (i == 0) rp[0] = 0;
    }
  }
  grid.sync();

  // ---- phase 3: scatter ----
  for (int e = gid; e < nE1; e += gstride) {
    int s, d;
    if (e < E1) { s = es1[e]; d = ed1[e]; } else { s = e - E1; d = s; }
    int pos = atomicAdd(&cnt1[d], 1);
    csr1[pos] = s;
  }
  for (int e = gid; e < nE2; e += gstride) {
    int s, d;
    if (e < E2) { s = es2[e]; d = ed2[e]; } else { s = e - E2; d = s; }
    int pos = atomicAdd(&cnt2[d], 1);
    csr2[pos] = s;
  }
}

// ---------- merged fused GATv2: single-fetch, degree-specialized ----------
// (verified baseline kernel, unchanged: 110.2 us/dispatch)
__global__ __launch_bounds__(256) void gat_dst2(
    const int* __restrict__ rp1, const int* __restrict__ csr1,
    const __half* __restrict__ xl1, const float* __restrict__ xr1,
    const float* __restrict__ att1, const float* __restrict__ bias1,
    float* __restrict__ out1, int nd1,
    const int* __restrict__ rp2, const int* __restrict__ csr2,
    const __half* __restrict__ xl2, const float* __restrict__ xr2,
    const float* __restrict__ att2, const float* __restrict__ bias2,
    float* __restrict__ out2, int nd2, int split) {
  __shared__ __align__(16) float tile[4][EPR * 64];  // 4 waves x 4KB, private

  const int b = blockIdx.x;
  const int* rp; const int* csr; const __half* xl; const float *xr, *att, *bias;
  float* out; int nd, d0;
  if (b < split) {
    rp = rp1; csr = csr1; xl = xl1; xr = xr1; att = att1; bias = bias1;
    out = out1; nd = nd1; d0 = b * 4;
  } else {
    rp = rp2; csr = csr2; xl = xl2; xr = xr2; att = att2; bias = bias2;
    out = out2; nd = nd2; d0 = (b - split) * 4;
  }
  const int w = threadIdx.x >> 6;
  const int d = d0 + w;
  if (d >= nd) return;
  const int h = threadIdx.x & 63;
  const unsigned h2 = (unsigned)h * 2u;          // byte offset of feature h (fp16)
  const char* xlb = (const char*)xl;
  float* tl = tile[w];

  const float xr_h = xr[(size_t)d * H + h];
  const float a = att[h];
  const float a06 = 0.6f * a, a04 = 0.4f * a;
  const float bias_h = bias[h];
  // wave-uniform bounds -> SGPRs (enables s_load for csr index fetches)
  const int sbeg = __builtin_amdgcn_readfirstlane(rp[d]);
  const int send = __builtin_amdgcn_readfirstlane(rp[d + 1]);

  const int r = h & 15;          // transpose: my edge row
  const int q = h >> 4;          // quarter of that row
  const int pr = (q << 2) ^ r;   // xor piece for transpose reads

  float o;  // pre-activation output

  if (send - sbeg <= EPR) {
    // ================= fast path: single round, plain softmax =================
    const int cnt = send - sbeg;   // may be 0 (isolated dst) -> out = bias
    const int* csw = csr + sbeg;   // uniform base -> scalar loads
    float v[EPR];
#pragma unroll
    for (int qq = 0; qq < EPR / 4; ++qq) {
      if (qq * 4 < cnt) {  // wave-uniform
#pragma unroll
        for (int i = 0; i < 4; ++i) {
          const int k = qq * 4 + i;
          int j = k < cnt ? k : cnt - 1;   // uniform clamped dup
          unsigned src = (unsigned)csw[j]; // s_load (uniform addr)
          v[k] = __half2float(*(const __half*)(xlb + ((src << 7) | h2)));
        }
      }
    }
#pragma unroll
    for (int qq = 0; qq < EPR / 4; ++qq) {
      if (qq * 4 < cnt) {
#pragma unroll
        for (int i = 0; i < 4; ++i) {
          const int k = qq * 4 + i;
          float p = v[k] + xr_h;
          tl[(k << 6) | (h ^ (k << 2))] = fmaf(p, a06, fabsf(p) * a04);
        }
      }
    }
    const float4* t4 = (const float4*)tl;
    float t0 = 0.f, t1 = 0.f, t2 = 0.f, t3 = 0.f;
#pragma unroll
    for (int c = 0; c < 4; ++c) {
      float4 q4 = t4[(r << 4) | (pr ^ c)];
      t0 += q4.x; t1 += q4.y; t2 += q4.z; t3 += q4.w;
    }
    float t = (t0 + t1) + (t2 + t3);
    t += __shfl_xor(t, 16, 64);
    t += __shfl_xor(t, 32, 64);
    t = (r < cnt) ? t : -3.0e38f;

    float M = t;
#pragma unroll
    for (int mk = 1; mk <= 8; mk <<= 1) M = fmaxf(M, __shfl_xor(M, mk, 64));
    float e = __expf(t - M);
    float S = e;
#pragma unroll
    for (int mk = 1; mk <= 8; mk <<= 1) S += __shfl_xor(S, mk, 64);
    if (h < 16) tl[h] = e;

    float P = 0.f;
#pragma unroll
    for (int qq = 0; qq < EPR / 4; ++qq) {
      if (qq * 4 < cnt) {
        float4 w4 = ((const float4*)tl)[qq];
        P += w4.x * v[qq * 4 + 0];
        P += w4.y * v[qq * 4 + 1];
        P += w4.z * v[qq * 4 + 2];
        P += w4.w * v[qq * 4 + 3];
      }
    }
    o = P / (S + 1e-16f) + bias_h;
  } else {
    // ================= multi-round path: flash + ping-pong prefetch ===========
    float m = -3.0e38f, s = 0.f, acc = 0.f;
    int base = sbeg;               // uniform
    float v[EPR], v2[EPR];

    // prologue: first round is full (send-sbeg > EPR)
    {
      const int* csw = csr + base;
#pragma unroll
      for (int k = 0; k < EPR; ++k) {
        unsigned src = (unsigned)csw[k];   // s_load
        v[k] = __half2float(*(const __half*)(xlb + ((src << 7) | h2)));
      }
    }

    // one round: consume vc (cnt edges at base), prefetch into vp
    auto round = [&](float (&vc)[EPR], float (&vp)[EPR]) -> bool {
      int cnt = send - base;
      if (cnt > EPR) cnt = EPR;
#pragma unroll
      for (int qq = 0; qq < EPR / 4; ++qq) {
        if (qq * 4 < cnt) {
#pragma unroll
          for (int i = 0; i < 4; ++i) {
            const int k = qq * 4 + i;
            float p = vc[k] + xr_h;
            tl[(k << 6) | (h ^ (k << 2))] = fmaf(p, a06, fabsf(p) * a04);
          }
        }
      }
      // prefetch next round (overlaps softmax chain below)
      const int nbase = base + EPR;
      int ncnt = send - nbase;
      const bool have_next = ncnt > 0;
      if (ncnt > EPR) ncnt = EPR;
      if (have_next) {
        const int* csn = csr + nbase;      // uniform base -> scalar loads
#pragma unroll
        for (int qq = 0; qq < EPR / 4; ++qq) {
          if (qq * 4 < ncnt) {
#pragma unroll
            for (int i = 0; i < 4; ++i) {
              const int k = qq * 4 + i;
              int j = k < ncnt ? k : ncnt - 1;
              unsigned src = (unsigned)csn[j];
              vp[k] = __half2float(*(const __half*)(xlb + ((src << 7) | h2)));
            }
          }
        }
      }
      const float4* t4 = (const float4*)tl;
      float t0 = 0.f, t1 = 0.f, t2 = 0.f, t3 = 0.f;
#pragma unroll
      for (int c = 0; c < 4; ++c) {
        float4 q4 = t4[(r << 4) | (pr ^ c)];
        t0 += q4.x; t1 += q4.y; t2 += q4.z; t3 += q4.w;
      }
      float t = (t0 + t1) + (t2 + t3);
      t += __shfl_xor(t, 16, 64);
      t += __shfl_xor(t, 32, 64);
      t = (r < cnt) ? t : -3.0e38f;

      float M = t;
#pragma unroll
      for (int mk = 1; mk <= 8; mk <<= 1) M = fmaxf(M, __shfl_xor(M, mk, 64));
      float e = __expf(t - M);
      float S = e;
#pragma unroll
      for (int mk = 1; mk <= 8; mk <<= 1) S += __shfl_xor(S, mk, 64);
      if (h < 16) tl[h] = e;

      float nm = fmaxf(m, M);
      float a_old = __expf(m - nm);
      float a_new = __expf(M - nm);
      float P = 0.f;
#pragma unroll
      for (int qq = 0; qq < EPR / 4; ++qq) {
        if (qq * 4 < cnt) {
          float4 w4 = ((const float4*)tl)[qq];
          P += w4.x * vc[qq * 4 + 0];
          P += w4.y * vc[qq * 4 + 1];
          P += w4.z * vc[qq * 4 + 2];
          P += w4.w * vc[qq * 4 + 3];
        }
      }
      s = s * a_old + S * a_new;
      acc = acc * a_old + P * a_new;
      m = nm;
      base = nbase;
      return have_next;
    };

    for (;;) {
      if (!round(v, v2)) break;   // consume v, prefetch v2
      if (!round(v2, v)) break;   // consume v2, prefetch v
    }
    o = acc / (s + 1e-16f) + bias_h;
  }

  out[(size_t)d * H + h] = selu_f(o);
}

// ---------- launch ----------
extern "C" void kernel_launch(void* const* d_in, const int* in_sizes, int n_in,
                              void* d_out, int out_size, void* d_ws, size_t ws_size,
                              hipStream_t stream) {
  const float* x_user = (const float*)d_in[0];
  const float* x_movie = (const float*)d_in[1];
  const int* e_u2m = (const int*)d_in[2];
  const int* e_m2u = (const int*)d_in[3];
  const float* Wl = (const float*)d_in[4];
  const float* bl = (const float*)d_in[5];
  const float* Wr = (const float*)d_in[6];
  const float* br = (const float*)d_in[7];
  const float* att = (const float*)d_in[8];
  const float* bias = (const float*)d_in[9];

  const int n_user = in_sizes[0] / H;
  const int n_movie = in_sizes[1] / H;
  const int E1 = in_sizes[2] / 2;  // user->movie (dst = movie)
  const int E2 = in_sizes[3] / 2;  // movie->user (dst = user)
  const int n_loop = n_user < n_movie ? n_user : n_movie;
  const int nE1 = E1 + n_loop;
  const int nE2 = E2 + n_loop;

  float* ws = (float*)d_ws;
  size_t o = 0;
  __half* xl_u2m = (__half*)(ws + o); o += (size_t)n_user * H / 2;
  __half* xl_m2u = (__half*)(ws + o); o += (size_t)n_movie * H / 2;
  float* xr_u2m = ws + o; o += (size_t)n_movie * H;
  float* xr_m2u = ws + o; o += (size_t)n_user * H;

  int* cntM = (int*)(ws + o); o += n_movie;          // graph1 counts/cursors
  int* cntU = (int*)(ws + o); o += n_user;           // graph2 (contiguous with cntM)
  int* rp1  = (int*)(ws + o); o += n_movie + 1;
  int* rp2  = (int*)(ws + o); o += n_user + 1;
  int* csr1 = (int*)(ws + o); o += nE1;
  int* csr2 = (int*)(ws + o); o += nE2;
  int* csum = (int*)(ws + o); o += 1024;

  float* out_u = (float*)d_out;
  float* out_m = out_u + (size_t)n_user * H;

  const int su = (n_user + 127) / 128;
  const int sm = (n_movie + 127) / 128;
  const int split1 = (n_movie + 3) / 4;   // gat: movie blocks (long, launch first)
  const int split2 = (n_user + 3) / 4;    // gat: user blocks
  const int C1 = (n_movie + 255) / 256;   // scan chunks, graph1
  const int C2 = (n_user + 255) / 256;    // scan chunks, graph2

  // ---- CSR build: one cooperative kernel (6 kernels fused; launch-overhead cut) ----
  hipMemsetAsync(cntM, 0, (size_t)(n_movie + n_user) * sizeof(int), stream);
  {
    const int* es1 = e_u2m;      const int* ed1 = e_u2m + E1;
    const int* es2 = e_m2u;      const int* ed2 = e_m2u + E2;
    int E1v = E1, nE1v = nE1, nd1v = n_movie;
    int E2v = E2, nE2v = nE2, nd2v = n_user;
    int C1v = C1, C2v = C2;
    void* args[] = {
      (void*)&es1, (void*)&ed1, (void*)&E1v, (void*)&nE1v, (void*)&nd1v,
      (void*)&cntM, (void*)&rp1, (void*)&csr1,
      (void*)&es2, (void*)&ed2, (void*)&E2v, (void*)&nE2v, (void*)&nd2v,
      (void*)&cntU, (void*)&rp2, (void*)&csr2,
      (void*)&csum, (void*)&C1v, (void*)&C2v };
    hipLaunchCooperativeKernel((const void*)csr_build, dim3(CSRB), dim3(256),
                               args, 0, stream);
  }

  for (int l = 0; l < 2; ++l) {
    const float* cu = (l == 0) ? x_user : out_u;
    const float* cm = (l == 0) ? x_movie : out_m;
    const int p0 = l * 2 + 0;  // user->movie params
    const int p1 = l * 2 + 1;  // movie->user params

    gemm64_split<<<2 * (su + sm), 256, 0, stream>>>(
        cu, cm,
        Wl + (size_t)p0 * H * H, bl + (size_t)p0 * H,   // user C0 = Wl[p0] (fp16)
        Wr + (size_t)p1 * H * H, br + (size_t)p1 * H,   // user C1 = Wr[p1] (fp32)
        Wl + (size_t)p1 * H * H, bl + (size_t)p1 * H,   // movie C0 = Wl[p1] (fp16)
        Wr + (size_t)p0 * H * H, br + (size_t)p0 * H,   // movie C1 = Wr[p0] (fp32)
        xl_u2m, xr_m2u, xl_m2u, xr_u2m,
        n_user, n_movie, su, sm);

    gat_dst2<<<split1 + split2, 256, 0, stream>>>(
        rp1, csr1, xl_u2m, xr_u2m, att + (size_t)p0 * H, bias + (size_t)p0 * H,
        out_m, n_movie,
        rp2, csr2, xl_m2u, xr_m2u, att + (size_t)p1 * H, bias + (size_t)p1 * H,
        out_u, n_user, split1);
  }
}

// Round 7
// 421.131 us; speedup vs baseline: 2.5152x; 2.5152x over previous
//
#include <hip/hip_runtime.h>
#include <hip/hip_fp16.h>
#include <cstdint>

#define H 64
#define EPR 16   // edges per round in gat (16 -> 4KB tile/wave)
#define NB 120   // partition blocks per graph (pass A/C chunking)

__device__ __forceinline__ float selu_f(float x) {
  const float sc = 1.0507009873554805f;
  const float al = 1.6732632423543772f;
  return x > 0.f ? sc * x : sc * al * (expf(x) - 1.f);
}

// ---------- GEMM v3: 128 rows/block, 8 col-groups x 4 rows/thread ----------
// split (2 rows, 16 cols/thread) was LDS-bound: 66 LDS cyc vs 64 VALU cyc per k.
// Here per k per thread: 2x b128 W (8 cols) + amortized 1x b128 A (4 rows,
// read every 4 k) = ~36 LDS cyc for 32 FMA (64 VALU cyc) -> VALU-bound.
// A stride 68 floats: b128-aligned (272B rows) and conflict-free ((4r+k)%32
// covers all banks); W reads 2-way aliased (free per m136).
// Per-output summation order identical to dual2/split -> bit-identical C.
__global__ __launch_bounds__(256) void gemm64_v3(
    const float* __restrict__ Au, const float* __restrict__ Am,
    const float* __restrict__ W0u, const float* __restrict__ b0u,
    const float* __restrict__ W1u, const float* __restrict__ b1u,
    const float* __restrict__ W0m, const float* __restrict__ b0m,
    const float* __restrict__ W1m, const float* __restrict__ b1m,
    __half* __restrict__ C0u, float* __restrict__ C1u,
    __half* __restrict__ C0m, float* __restrict__ C1m,
    int Nu, int Nm, int su, int sm) {
  __shared__ float Ws[64 * 64];
  __shared__ float As[128 * 68];   // stride 68: 16B-aligned rows, conflict-free
  __shared__ float bs[64];

  const int b = blockIdx.x;
  const float *A, *W, *bias; __half* Ch = nullptr; float* Cf = nullptr;
  int N, blk; bool half_out;
  if (b < su)             { A = Au; W = W0u; bias = b0u; Ch = C0u; N = Nu; blk = b;             half_out = true; }
  else if (b < 2 * su)    { A = Au; W = W1u; bias = b1u; Cf = C1u; N = Nu; blk = b - su;        half_out = false; }
  else if (b < 2*su + sm) { A = Am; W = W0m; bias = b0m; Ch = C0m; N = Nm; blk = b - 2*su;      half_out = true; }
  else                    { A = Am; W = W1m; bias = b1m; Cf = C1m; N = Nm; blk = b - 2*su - sm; half_out = false; }

  const int tid = threadIdx.x;
  for (int i = tid; i < 1024; i += 256) ((float4*)Ws)[i] = ((const float4*)W)[i];
  if (tid < 64) bs[tid] = bias[tid];

  const int row0 = blk * 128;
  for (int i = tid; i < 2048; i += 256) {
    int r = i >> 4, c4 = i & 15;
    int row = row0 + r;
    float4 v = make_float4(0.f, 0.f, 0.f, 0.f);
    if (row < N) v = ((const float4*)(A + (size_t)row * H))[c4];
    *(float4*)&As[r * 68 + c4 * 4] = v;
  }
  __syncthreads();

  const int cg = tid & 7;   // 8-col group
  const int rs = tid >> 3;  // 0..31; rows rs + 32*i
  float acc[4][8];
#pragma unroll
  for (int i = 0; i < 4; ++i)
#pragma unroll
    for (int j = 0; j < 8; ++j) acc[i][j] = bs[cg * 8 + j];

  for (int kt = 0; kt < 16; ++kt) {
    float4 a4[4];
#pragma unroll
    for (int i = 0; i < 4; ++i)
      a4[i] = *(const float4*)&As[(rs + 32 * i) * 68 + kt * 4];
#pragma unroll
    for (int kk = 0; kk < 4; ++kk) {
      const int k = kt * 4 + kk;
      const float4* wr = (const float4*)&Ws[k * 64 + cg * 8];
      float4 w0 = wr[0], w1 = wr[1];
      float a[4];
      a[0] = (kk == 0) ? a4[0].x : (kk == 1) ? a4[0].y : (kk == 2) ? a4[0].z : a4[0].w;
      a[1] = (kk == 0) ? a4[1].x : (kk == 1) ? a4[1].y : (kk == 2) ? a4[1].z : a4[1].w;
      a[2] = (kk == 0) ? a4[2].x : (kk == 1) ? a4[2].y : (kk == 2) ? a4[2].z : a4[2].w;
      a[3] = (kk == 0) ? a4[3].x : (kk == 1) ? a4[3].y : (kk == 2) ? a4[3].z : a4[3].w;
#pragma unroll
      for (int i = 0; i < 4; ++i) {
        acc[i][0] = fmaf(a[i], w0.x, acc[i][0]);
        acc[i][1] = fmaf(a[i], w0.y, acc[i][1]);
        acc[i][2] = fmaf(a[i], w0.z, acc[i][2]);
        acc[i][3] = fmaf(a[i], w0.w, acc[i][3]);
        acc[i][4] = fmaf(a[i], w1.x, acc[i][4]);
        acc[i][5] = fmaf(a[i], w1.y, acc[i][5]);
        acc[i][6] = fmaf(a[i], w1.z, acc[i][6]);
        acc[i][7] = fmaf(a[i], w1.w, acc[i][7]);
      }
    }
  }

#pragma unroll
  for (int i = 0; i < 4; ++i) {
    const int row = row0 + rs + 32 * i;
    if (row >= N) continue;
    if (half_out) {
      unsigned pu[4];
#pragma unroll
      for (int j2 = 0; j2 < 4; ++j2) {
        __half2 t = __floats2half2_rn(acc[i][2 * j2], acc[i][2 * j2 + 1]);
        pu[j2] = *(unsigned*)&t;
      }
      *(uint4*)(Ch + (size_t)row * H + cg * 8) = make_uint4(pu[0], pu[1], pu[2], pu[3]);
    } else {
      float4* c1 = (float4*)(Cf + (size_t)row * H + cg * 8);
      c1[0] = make_float4(acc[i][0], acc[i][1], acc[i][2], acc[i][3]);
      c1[1] = make_float4(acc[i][4], acc[i][5], acc[i][6], acc[i][7]);
    }
  }
}

// ---------- Pass A: per-block bucket histograms (LDS only, no device atomics) ----------
__global__ __launch_bounds__(256) void bucket_hist(
    const int* __restrict__ ed1, int E1r, int n1e, int sh1, int B1, int* __restrict__ mat1,
    const int* __restrict__ ed2, int E2r, int n2e, int sh2, int B2, int* __restrict__ mat2) {
  __shared__ int hist[640];
  int b = blockIdx.x;
  const int* ed; int Er, ne, sh, Bn, blk; int* mat;
  if (b < NB) { ed = ed1; Er = E1r; ne = n1e; sh = sh1; Bn = B1; mat = mat1; blk = b; }
  else { ed = ed2; Er = E2r; ne = n2e; sh = sh2; Bn = B2; mat = mat2; blk = b - NB; }
  for (int i = threadIdx.x; i < Bn; i += 256) hist[i] = 0;
  __syncthreads();
  int chunk = (ne + NB - 1) / NB;
  int lo = blk * chunk, hi = lo + chunk;
  if (hi > ne) hi = ne;
  for (int e = lo + threadIdx.x; e < hi; e += 256) {
    int d = (e < Er) ? ed[e] : (e - Er);
    atomicAdd(&hist[d >> sh], 1);  // LDS atomic
  }
  __syncthreads();
  for (int i = threadIdx.x; i < Bn; i += 256) mat[(size_t)i * NB + blk] = hist[i];
}

// ---------- scan chain ----------
__global__ __launch_bounds__(256) void scan_partial2(
    const int* __restrict__ cnt1, int n1, int* __restrict__ psum1, int* __restrict__ bsum1,
    const int* __restrict__ cnt2, int n2, int* __restrict__ psum2, int* __restrict__ bsum2,
    int split) {
  __shared__ int sh[256];
  int b = blockIdx.x;
  const int* cnt; int n; int* psum; int* bsum; int lb;
  if (b < split) { cnt = cnt1; n = n1; psum = psum1; bsum = bsum1; lb = b; }
  else { cnt = cnt2; n = n2; psum = psum2; bsum = bsum2; lb = b - split; }
  int i = lb * 256 + threadIdx.x;
  int tid = threadIdx.x;
  sh[tid] = (i < n) ? cnt[i] : 0;
  __syncthreads();
  for (int off = 1; off < 256; off <<= 1) {
    int t = (tid >= off) ? sh[tid - off] : 0;
    __syncthreads();
    if (tid >= off) sh[tid] += t;
    __syncthreads();
  }
  if (i < n) psum[i] = sh[tid];
  if (tid == 255) bsum[lb] = sh[255];
}

__global__ __launch_bounds__(256) void scan_bsums2(
    int* __restrict__ bsum1, int nb1, int* __restrict__ bsum2, int nb2) {
  __shared__ int sh[256];
  const int tid = threadIdx.x;
  for (int which = 0; which < 2; ++which) {
    int* bsum = which ? bsum2 : bsum1;
    int nb = which ? nb2 : nb1;
    int run = 0;
    for (int start = 0; start < nb; start += 256) {
      int i = start + tid;
      int v = (i < nb) ? bsum[i] : 0;
      __syncthreads();
      sh[tid] = v;
      __syncthreads();
      for (int off = 1; off < 256; off <<= 1) {
        int t = (tid >= off) ? sh[tid - off] : 0;
        __syncthreads();
        if (tid >= off) sh[tid] += t;
        __syncthreads();
      }
      if (i < nb) bsum[i] = run + sh[tid] - v;  // exclusive
      run += sh[255];
      __syncthreads();
    }
  }
}

__global__ __launch_bounds__(256) void finalize_excl2(
    const int* __restrict__ cnt1, const int* __restrict__ psum1,
    const int* __restrict__ bsum1, int n1, int* __restrict__ excl1,
    const int* __restrict__ cnt2, const int* __restrict__ psum2,
    const int* __restrict__ bsum2, int n2, int* __restrict__ excl2, int split) {
  int b = blockIdx.x;
  const int *cnt, *psum, *bsum; int n; int* excl; int lb;
  if (b < split) { cnt = cnt1; psum = psum1; bsum = bsum1; n = n1; excl = excl1; lb = b; }
  else { cnt = cnt2; psum = psum2; bsum = bsum2; n = n2; excl = excl2; lb = b - split; }
  int i = lb * 256 + threadIdx.x;
  if (i >= n) return;
  excl[i] = psum[i] + bsum[lb] - cnt[i];
}

// ---------- Pass C: partition edges into bucket order via private LDS cursors ----------
__global__ __launch_bounds__(256) void bucket_part(
    const int* __restrict__ es1, const int* __restrict__ ed1, int E1r, int n1e,
    int sh1, int B1, const int* __restrict__ excl1, unsigned* __restrict__ part1,
    const int* __restrict__ es2, const int* __restrict__ ed2, int E2r, int n2e,
    int sh2, int B2, const int* __restrict__ excl2, unsigned* __restrict__ part2) {
  __shared__ int cur[640];
  int b = blockIdx.x;
  const int *es, *ed, *excl; int Er, ne, sh, Bn, blk; unsigned* part;
  if (b < NB) { es = es1; ed = ed1; Er = E1r; ne = n1e; sh = sh1; Bn = B1; excl = excl1; part = part1; blk = b; }
  else { es = es2; ed = ed2; Er = E2r; ne = n2e; sh = sh2; Bn = B2; excl = excl2; part = part2; blk = b - NB; }
  for (int i = threadIdx.x; i < Bn; i += 256) cur[i] = excl[(size_t)i * NB + blk];
  __syncthreads();
  int chunk = (ne + NB - 1) / NB;
  int lo = blk * chunk, hi = lo + chunk;
  if (hi > ne) hi = ne;
  const unsigned lmask = (1u << sh) - 1u;
  for (int e = lo + threadIdx.x; e < hi; e += 256) {
    int s, d;
    if (e < Er) { s = es[e]; d = ed[e]; } else { s = e - Er; d = s; }
    int bkt = d >> sh;
    int pos = atomicAdd(&cur[bkt], 1);  // LDS atomic; (block,bucket) ranges disjoint
    part[pos] = (((unsigned)d & lmask) << 18) | (unsigned)s;
  }
}

// ---------- Pass D: per-bucket LDS counting sort (R<=256) -> row_ptr + csr ----------
__global__ __launch_bounds__(256) void bucket_sort(
    const unsigned* __restrict__ part1, const int* __restrict__ excl1,
    int n1e, int sh1, int B1, int nd1, int* __restrict__ rp1, int* __restrict__ csr1,
    const unsigned* __restrict__ part2, const int* __restrict__ excl2,
    int n2e, int sh2, int B2, int nd2, int* __restrict__ rp2, int* __restrict__ csr2) {
  __shared__ int cnt_s[256];
  __shared__ int scan_s[256];
  int b = blockIdx.x;
  const unsigned* part; const int* excl; int ne, sh, Bn, nd, bkt; int *rp, *csr;
  if (b < B1) { part = part1; excl = excl1; ne = n1e; sh = sh1; Bn = B1; nd = nd1; rp = rp1; csr = csr1; bkt = b; }
  else { part = part2; excl = excl2; ne = n2e; sh = sh2; Bn = B2; nd = nd2; rp = rp2; csr = csr2; bkt = b - B1; }
  const int tid = threadIdx.x;
  const int dbase = bkt << sh;
  const int R = 1 << sh;          // <= 256
  int rcap = nd - dbase;
  if (rcap > R) rcap = R;
  const int base = excl[(size_t)bkt * NB];
  const int endv = (bkt == Bn - 1) ? ne : excl[(size_t)(bkt + 1) * NB];

  cnt_s[tid] = 0;
  __syncthreads();
  for (int i = base + tid; i < endv; i += 256)
    atomicAdd(&cnt_s[part[i] >> 18], 1);
  __syncthreads();
  int c = cnt_s[tid];
  scan_s[tid] = c;
  __syncthreads();
  for (int off = 1; off < 256; off <<= 1) {
    int t = (tid >= off) ? scan_s[tid - off] : 0;
    __syncthreads();
    if (tid >= off) scan_s[tid] += t;
    __syncthreads();
  }
  if (tid < rcap) rp[dbase + tid + 1] = base + scan_s[tid];
  cnt_s[tid] = base + scan_s[tid] - c;   // exclusive write cursor
  if (tid == 0 && bkt == 0) rp[0] = 0;
  __syncthreads();
  for (int i = base + tid; i < endv; i += 256) {
    unsigned p = part[i];
    int dl = p >> 18;
    int pos = atomicAdd(&cnt_s[dl], 1);  // LDS atomic
    csr[pos] = (int)(p & 0x3FFFFu);
  }
}

// ---------- merged fused GATv2: single-fetch, degree-specialized ----------
// (verified baseline kernel, unchanged: 110.2 us/dispatch)
__global__ __launch_bounds__(256) void gat_dst2(
    const int* __restrict__ rp1, const int* __restrict__ csr1,
    const __half* __restrict__ xl1, const float* __restrict__ xr1,
    const float* __restrict__ att1, const float* __restrict__ bias1,
    float* __restrict__ out1, int nd1,
    const int* __restrict__ rp2, const int* __restrict__ csr2,
    const __half* __restrict__ xl2, const float* __restrict__ xr2,
    const float* __restrict__ att2, const float* __restrict__ bias2,
    float* __restrict__ out2, int nd2, int split) {
  __shared__ __align__(16) float tile[4][EPR * 64];  // 4 waves x 4KB, private

  const int b = blockIdx.x;
  const int* rp; const int* csr; const __half* xl; const float *xr, *att, *bias;
  float* out; int nd, d0;
  if (b < split) {
    rp = rp1; csr = csr1; xl = xl1; xr = xr1; att = att1; bias = bias1;
    out = out1; nd = nd1; d0 = b * 4;
  } else {
    rp = rp2; csr = csr2; xl = xl2; xr = xr2; att = att2; bias = bias2;
    out = out2; nd = nd2; d0 = (b - split) * 4;
  }
  const int w = threadIdx.x >> 6;
  const int d = d0 + w;
  if (d >= nd) return;
  const int h = threadIdx.x & 63;
  const unsigned h2 = (unsigned)h * 2u;          // byte offset of feature h (fp16)
  const char* xlb = (const char*)xl;
  float* tl = tile[w];

  const float xr_h = xr[(size_t)d * H + h];
  const float a = att[h];
  const float a06 = 0.6f * a, a04 = 0.4f * a;
  const float bias_h = bias[h];
  // wave-uniform bounds -> SGPRs (enables s_load for csr index fetches)
  const int sbeg = __builtin_amdgcn_readfirstlane(rp[d]);
  const int send = __builtin_amdgcn_readfirstlane(rp[d + 1]);

  const int r = h & 15;          // transpose: my edge row
  const int q = h >> 4;          // quarter of that row
  const int pr = (q << 2) ^ r;   // xor piece for transpose reads

  float o;  // pre-activation output

  if (send - sbeg <= EPR) {
    // ================= fast path: single round, plain softmax =================
    const int cnt = send - sbeg;   // may be 0 (isolated dst) -> out = bias
    const int* csw = csr + sbeg;   // uniform base -> scalar loads
    float v[EPR];
#pragma unroll
    for (int qq = 0; qq < EPR / 4; ++qq) {
      if (qq * 4 < cnt) {  // wave-uniform
#pragma unroll
        for (int i = 0; i < 4; ++i) {
          const int k = qq * 4 + i;
          int j = k < cnt ? k : cnt - 1;   // uniform clamped dup
          unsigned src = (unsigned)csw[j]; // s_load (uniform addr)
          v[k] = __half2float(*(const __half*)(xlb + ((src << 7) | h2)));
        }
      }
    }
#pragma unroll
    for (int qq = 0; qq < EPR / 4; ++qq) {
      if (qq * 4 < cnt) {
#pragma unroll
        for (int i = 0; i < 4; ++i) {
          const int k = qq * 4 + i;
          float p = v[k] + xr_h;
          tl[(k << 6) | (h ^ (k << 2))] = fmaf(p, a06, fabsf(p) * a04);
        }
      }
    }
    const float4* t4 = (const float4*)tl;
    float t0 = 0.f, t1 = 0.f, t2 = 0.f, t3 = 0.f;
#pragma unroll
    for (int c = 0; c < 4; ++c) {
      float4 q4 = t4[(r << 4) | (pr ^ c)];
      t0 += q4.x; t1 += q4.y; t2 += q4.z; t3 += q4.w;
    }
    float t = (t0 + t1) + (t2 + t3);
    t += __shfl_xor(t, 16, 64);
    t += __shfl_xor(t, 32, 64);
    t = (r < cnt) ? t : -3.0e38f;

    float M = t;
#pragma unroll
    for (int mk = 1; mk <= 8; mk <<= 1) M = fmaxf(M, __shfl_xor(M, mk, 64));
    float e = __expf(t - M);
    float S = e;
#pragma unroll
    for (int mk = 1; mk <= 8; mk <<= 1) S += __shfl_xor(S, mk, 64);
    if (h < 16) tl[h] = e;

    float P = 0.f;
#pragma unroll
    for (int qq = 0; qq < EPR / 4; ++qq) {
      if (qq * 4 < cnt) {
        float4 w4 = ((const float4*)tl)[qq];
        P += w4.x * v[qq * 4 + 0];
        P += w4.y * v[qq * 4 + 1];
        P += w4.z * v[qq * 4 + 2];
        P += w4.w * v[qq * 4 + 3];
      }
    }
    o = P / (S + 1e-16f) + bias_h;
  } else {
    // ================= multi-round path: flash + ping-pong prefetch ===========
    float m = -3.0e38f, s = 0.f, acc = 0.f;
    int base = sbeg;               // uniform
    float v[EPR], v2[EPR];

    // prologue: first round is full (send-sbeg > EPR)
    {
      const int* csw = csr + base;
#pragma unroll
      for (int k = 0; k < EPR; ++k) {
        unsigned src = (unsigned)csw[k];   // s_load
        v[k] = __half2float(*(const __half*)(xlb + ((src << 7) | h2)));
      }
    }

    // one round: consume vc (cnt edges at base), prefetch into vp
    auto round = [&](float (&vc)[EPR], float (&vp)[EPR]) -> bool {
      int cnt = send - base;
      if (cnt > EPR) cnt = EPR;
#pragma unroll
      for (int qq = 0; qq < EPR / 4; ++qq) {
        if (qq * 4 < cnt) {
#pragma unroll
          for (int i = 0; i < 4; ++i) {
            const int k = qq * 4 + i;
            float p = vc[k] + xr_h;
            tl[(k << 6) | (h ^ (k << 2))] = fmaf(p, a06, fabsf(p) * a04);
          }
        }
      }
      // prefetch next round (overlaps softmax chain below)
      const int nbase = base + EPR;
      int ncnt = send - nbase;
      const bool have_next = ncnt > 0;
      if (ncnt > EPR) ncnt = EPR;
      if (have_next) {
        const int* csn = csr + nbase;      // uniform base -> scalar loads
#pragma unroll
        for (int qq = 0; qq < EPR / 4; ++qq) {
          if (qq * 4 < ncnt) {
#pragma unroll
            for (int i = 0; i < 4; ++i) {
              const int k = qq * 4 + i;
              int j = k < ncnt ? k : ncnt - 1;
              unsigned src = (unsigned)csn[j];
              vp[k] = __half2float(*(const __half*)(xlb + ((src << 7) | h2)));
            }
          }
        }
      }
      const float4* t4 = (const float4*)tl;
      float t0 = 0.f, t1 = 0.f, t2 = 0.f, t3 = 0.f;
#pragma unroll
      for (int c = 0; c < 4; ++c) {
        float4 q4 = t4[(r << 4) | (pr ^ c)];
        t0 += q4.x; t1 += q4.y; t2 += q4.z; t3 += q4.w;
      }
      float t = (t0 + t1) + (t2 + t3);
      t += __shfl_xor(t, 16, 64);
      t += __shfl_xor(t, 32, 64);
      t = (r < cnt) ? t : -3.0e38f;

      float M = t;
#pragma unroll
      for (int mk = 1; mk <= 8; mk <<= 1) M = fmaxf(M, __shfl_xor(M, mk, 64));
      float e = __expf(t - M);
      float S = e;
#pragma unroll
      for (int mk = 1; mk <= 8; mk <<= 1) S += __shfl_xor(S, mk, 64);
      if (h < 16) tl[h] = e;

      float nm = fmaxf(m, M);
      float a_old = __expf(m - nm);
      float a_new = __expf(M - nm);
      float P = 0.f;
#pragma unroll
      for (int qq = 0; qq < EPR / 4; ++qq) {
        if (qq * 4 < cnt) {
          float4 w4 = ((const float4*)tl)[qq];
          P += w4.x * vc[qq * 4 + 0];
          P += w4.y * vc[qq * 4 + 1];
          P += w4.z * vc[qq * 4 + 2];
          P += w4.w * vc[qq * 4 + 3];
        }
      }
      s = s * a_old + S * a_new;
      acc = acc * a_old + P * a_new;
      m = nm;
      base = nbase;
      return have_next;
    };

    for (;;) {
      if (!round(v, v2)) break;   // consume v, prefetch v2
      if (!round(v2, v)) break;   // consume v2, prefetch v
    }
    o = acc / (s + 1e-16f) + bias_h;
  }

  out[(size_t)d * H + h] = selu_f(o);
}

// ---------- launch ----------
extern "C" void kernel_launch(void* const* d_in, const int* in_sizes, int n_in,
                              void* d_out, int out_size, void* d_ws, size_t ws_size,
                              hipStream_t stream) {
  const float* x_user = (const float*)d_in[0];
  const float* x_movie = (const float*)d_in[1];
  const int* e_u2m = (const int*)d_in[2];
  const int* e_m2u = (const int*)d_in[3];
  const float* Wl = (const float*)d_in[4];
  const float* bl = (const float*)d_in[5];
  const float* Wr = (const float*)d_in[6];
  const float* br = (const float*)d_in[7];
  const float* att = (const float*)d_in[8];
  const float* bias = (const float*)d_in[9];

  const int n_user = in_sizes[0] / H;
  const int n_movie = in_sizes[1] / H;
  const int E1 = in_sizes[2] / 2;  // user->movie (dst = movie)
  const int E2 = in_sizes[3] / 2;  // movie->user (dst = user)
  const int n_loop = n_user < n_movie ? n_user : n_movie;
  const int nE1 = E1 + n_loop;
  const int nE2 = E2 + n_loop;

  // smaller buckets -> 4x more pass-D blocks (SHM 5: 32 dsts, SHU 8: 256 dsts)
  const int SHM = 5, SHU = 8;
  const int Bm = (n_movie + (1 << SHM) - 1) >> SHM;   // ~625
  const int Bu = (n_user + (1 << SHU) - 1) >> SHU;    // ~391
  const int nmatM = Bm * NB, nmatU = Bu * NB;
  const int nbm = (nmatM + 255) / 256, nbu = (nmatU + 255) / 256;

  float* ws = (float*)d_ws;
  size_t o = 0;
  __half* xl_u2m = (__half*)(ws + o); o += (size_t)n_user * H / 2;
  __half* xl_m2u = (__half*)(ws + o); o += (size_t)n_movie * H / 2;
  float* xr_u2m = ws + o; o += (size_t)n_movie * H;
  float* xr_m2u = ws + o; o += (size_t)n_user * H;

  int* matM  = (int*)(ws + o); o += nmatM;
  int* psumM = (int*)(ws + o); o += nmatM;
  int* exclM = (int*)(ws + o); o += nmatM;
  int* matU  = (int*)(ws + o); o += nmatU;
  int* psumU = (int*)(ws + o); o += nmatU;
  int* exclU = (int*)(ws + o); o += nmatU;
  int* bsumM = (int*)(ws + o); o += 1024;
  int* bsumU = (int*)(ws + o); o += 1024;
  unsigned* partM = (unsigned*)(ws + o); o += nE1;
  unsigned* partU = (unsigned*)(ws + o); o += nE2;
  int* csr1 = (int*)(ws + o); o += nE1;
  int* csr2 = (int*)(ws + o); o += nE2;
  int* rp1  = (int*)(ws + o); o += n_movie + 1;
  int* rp2  = (int*)(ws + o); o += n_user + 1;

  float* out_u = (float*)d_out;
  float* out_m = out_u + (size_t)n_user * H;

  const int su = (n_user + 127) / 128;
  const int sm = (n_movie + 127) / 128;
  const int split1 = (n_movie + 3) / 4;   // gat: movie blocks (long, launch first)
  const int split2 = (n_user + 3) / 4;    // gat: user blocks

  // ---- CSR build: deterministic two-level bucket sort, zero device atomics ----
  bucket_hist<<<2 * NB, 256, 0, stream>>>(
      e_u2m + E1, E1, nE1, SHM, Bm, matM,
      e_m2u + E2, E2, nE2, SHU, Bu, matU);
  scan_partial2<<<nbm + nbu, 256, 0, stream>>>(
      matM, nmatM, psumM, bsumM, matU, nmatU, psumU, bsumU, nbm);
  scan_bsums2<<<1, 256, 0, stream>>>(bsumM, nbm, bsumU, nbu);
  finalize_excl2<<<nbm + nbu, 256, 0, stream>>>(
      matM, psumM, bsumM, nmatM, exclM,
      matU, psumU, bsumU, nmatU, exclU, nbm);
  bucket_part<<<2 * NB, 256, 0, stream>>>(
      e_u2m, e_u2m + E1, E1, nE1, SHM, Bm, exclM, partM,
      e_m2u, e_m2u + E2, E2, nE2, SHU, Bu, exclU, partU);
  bucket_sort<<<Bm + Bu, 256, 0, stream>>>(
      partM, exclM, nE1, SHM, Bm, n_movie, rp1, csr1,
      partU, exclU, nE2, SHU, Bu, n_user, rp2, csr2);

  for (int l = 0; l < 2; ++l) {
    const float* cu = (l == 0) ? x_user : out_u;
    const float* cm = (l == 0) ? x_movie : out_m;
    const int p0 = l * 2 + 0;  // user->movie params
    const int p1 = l * 2 + 1;  // movie->user params

    gemm64_v3<<<2 * (su + sm), 256, 0, stream>>>(
        cu, cm,
        Wl + (size_t)p0 * H * H, bl + (size_t)p0 * H,   // user C0 = Wl[p0] (fp16)
        Wr + (size_t)p1 * H * H, br + (size_t)p1 * H,   // user C1 = Wr[p1] (fp32)
        Wl + (size_t)p1 * H * H, bl + (size_t)p1 * H,   // movie C0 = Wl[p1] (fp16)
        Wr + (size_t)p0 * H * H, br + (size_t)p0 * H,   // movie C1 = Wr[p0] (fp32)
        xl_u2m, xr_m2u, xl_m2u, xr_u2m,
        n_user, n_movie, su, sm);

    gat_dst2<<<split1 + split2, 256, 0, stream>>>(
        rp1, csr1, xl_u2m, xr_u2m, att + (size_t)p0 * H, bias + (size_t)p0 * H,
        out_m, n_movie,
        rp2, csr2, xl_m2u, xr_m2u, att + (size_t)p1 * H, bias + (size_t)p1 * H,
        out_u, n_user, split1);
  }
}